// Round 1
// baseline (730.494 us; speedup 1.0000x reference)
//
#include <hip/hip_runtime.h>

#define T_N 1024
#define B_N 64
#define A_N 128
#define TP1 1025
// STOP_IX=0, CONT_IX=1

__device__ __forceinline__ float bcf(int x){ return __builtin_bit_cast(float, x); }
__device__ __forceinline__ int   bci(float x){ return __builtin_bit_cast(int, x); }

// ---- wave64 reductions via DPP (gfx9 row_shr / row_bcast ladder) ----
template<int CTRL, int RM>
__device__ __forceinline__ float dpp_add_step(float x){
  int t = __builtin_amdgcn_update_dpp(0, bci(x), CTRL, RM, 0xf, true);
  return x + bcf(t);
}
__device__ __forceinline__ float wave_sum64(float x){
  x = dpp_add_step<0x111,0xf>(x);   // row_shr:1
  x = dpp_add_step<0x112,0xf>(x);   // row_shr:2
  x = dpp_add_step<0x114,0xf>(x);   // row_shr:4
  x = dpp_add_step<0x118,0xf>(x);   // row_shr:8  -> lane15 of each row has row sum
  x = dpp_add_step<0x142,0xa>(x);   // row_bcast15 -> rows 1,3
  x = dpp_add_step<0x143,0xc>(x);   // row_bcast31 -> rows 2,3; lane63 = total
  return bcf(__builtin_amdgcn_readlane(bci(x), 63));
}
template<int CTRL, int RM>
__device__ __forceinline__ float dpp_max_step(float x){
  int t = __builtin_amdgcn_update_dpp(bci(-3.4e38f), bci(x), CTRL, RM, 0xf, false);
  return fmaxf(x, bcf(t));
}
__device__ __forceinline__ float wave_max64(float x){
  x = dpp_max_step<0x111,0xf>(x);
  x = dpp_max_step<0x112,0xf>(x);
  x = dpp_max_step<0x114,0xf>(x);
  x = dpp_max_step<0x118,0xf>(x);
  x = dpp_max_step<0x142,0xa>(x);
  x = dpp_max_step<0x143,0xc>(x);
  return bcf(__builtin_amdgcn_readlane(bci(x), 63));
}

// ---------------- K1: sequential scan, one wave ----------------
// State in scaled exp space: z[b] = exp(S_{i-1}[b] + C_{i-1}[b] - M).
// Per step: r = sum_b z*exp(stop)  -> R_i = M + log r - 0.5
//           z' = (z*exp(cont))*2^-e + exp(start)*kappa*mantissa(r),  M += e*ln2
// Rescale by 2^e (e = exponent of r): exact bookkeeping, no division.
__global__ __launch_bounds__(64) void scan_kernel(
    const int* __restrict__ actions,
    const float* __restrict__ action_logps,   // (1025,64,128)
    const float* __restrict__ stop_logps,     // (1025,64,2)
    const float* __restrict__ start_logps,    // (1025,64)
    float* __restrict__ out,
    float* __restrict__ u_ws,     // (1024,64)
    float* __restrict__ C_ws,     // (1024,64)
    float* __restrict__ Um_ws)    // (1024,64) running max_j u_j[b]
{
  const int lane = threadIdx.x;
  const float KAPPA = 0.60653065971263342f;  // e^-0.5
  const float LN2   = 0.69314718055994531f;

  float st0 = start_logps[lane];
  int   a0  = actions[0];
  float al0 = action_logps[lane * A_N + a0];
  float lp0 = __logf(wave_sum64(__expf(st0 + al0)));

  float z  = __expf(st0);   // M = 0
  float M  = 0.f;
  float C  = 0.f;
  float Um = st0;
  u_ws[lane]  = st0;
  C_ws[lane]  = 0.f;
  Um_ws[lane] = st0;

  const float2* stop2 = (const float2*)stop_logps;
  float2 sc = stop2[B_N + lane];          // i=1: [stop, cont]
  float  st = start_logps[B_N + lane];

  for (int i = 1; i < T_N; ++i) {
    int ip = (i + 1 < T_N) ? (i + 1) : i;   // clamped prefetch
    float2 sc_n = stop2[ip * B_N + lane];
    float  st_n = start_logps[ip * B_N + lane];

    float sw  = __expf(sc.x);
    float cwv = __expf(sc.y);
    float t   = z * sw;
    float zc  = z * cwv;                 // overlaps the reduction
    float stwk = __expf(st) * KAPPA;

    float r = wave_sum64(t);             // critical path
    int rb = bci(r);
    int e  = ((rb >> 23) & 255) - 126;   // r = mr * 2^e, mr in [0.5,1)
    float mr = bcf((rb & 0x007fffff) | 0x3f000000);
    z = ldexpf(zc, -e) + stwk * mr;      // new scaled state

    M += (float)e * LN2;
    float Ri = M + __logf(mr) - 0.5f;
    C += sc.y;
    float u = st + Ri - C;
    Um = fmaxf(Um, u);
    u_ws[i * B_N + lane]  = u;
    C_ws[i * B_N + lane]  = C;
    Um_ws[i * B_N + lane] = Um;

    sc = sc_n; st = st_n;
  }
  // final term: logsumexp_b(S_{T-1}+C_{T-1}+stop_logps[T,:,STOP])
  float stopT = stop_logps[(T_N * B_N + lane) * 2 + 0];
  float fr  = wave_sum64(z * __expf(stopT));
  float fin = M + __logf(fr);
  if (lane == 0) out[0] = -(lp0 + fin);
}

// ---------------- K2: per-i consistency + logp terms ----------------
__global__ __launch_bounds__(256) void cons_kernel(
    const int* __restrict__ actions,
    const float* __restrict__ action_logps,
    const float* __restrict__ cons_pen,   // (1025,1025,64); cp[j][i][b]
    const float* __restrict__ u_ws,
    const float* __restrict__ C_ws,
    const float* __restrict__ Um_ws,
    float* __restrict__ out)
{
  const int i    = T_N - 1 - (int)blockIdx.x;   // 1023 .. 1, big work first
  const int lane = threadIdx.x & 63;
  const int wv   = threadIdx.x >> 6;            // 0..3

  float Ci  = C_ws[i * B_N + lane];
  float Umx = Um_ws[i * B_N + lane];
  float Mi  = wave_max64(Ci + Umx);             // uniform stabilizer, args <= 0
  float cc  = Ci - Mi;

  float acc1 = 0.f;   // sum exp(u_j + cp + C_i - Mi)   -> cons_i
  float acc2 = 0.f;   // sum exp(u_j - Umx[b])          -> S_i[b]
  const float* cp_col = cons_pen + (size_t)i * B_N + lane;
  for (int j = wv; j <= i; j += 4) {
    float u  = u_ws[j * B_N + lane];
    float cp = cp_col[(size_t)j * (TP1 * B_N)];
    acc1 += __expf(u + cp + cc);
    acc2 += __expf(u - Umx);
  }

  __shared__ float s1[4];
  __shared__ float s2[4][64];
  float w1 = wave_sum64(acc1);
  if (lane == 0) s1[wv] = w1;
  s2[wv][lane] = acc2;
  __syncthreads();

  if (wv == 0) {
    float tot1 = s1[0] + s1[1] + s1[2] + s1[3];
    float a2   = s2[0][lane] + s2[1][lane] + s2[2][lane] + s2[3][lane];
    float cons_i = Mi + __logf(tot1);

    int   ai  = actions[i];
    float act = action_logps[((size_t)i * B_N + lane) * A_N + ai];
    float Sterm = Umx + __logf(a2) + Ci + act;     // S_i + C_i + act
    float mx  = wave_max64(Sterm);
    float ls  = wave_sum64(__expf(Sterm - mx));
    float logp_i = mx + __logf(ls);

    if (lane == 0) atomicAdd(out, cons_i - logp_i);
  }
}

extern "C" void kernel_launch(void* const* d_in, const int* in_sizes, int n_in,
                              void* d_out, int out_size, void* d_ws, size_t ws_size,
                              hipStream_t stream) {
  const int*   actions       = (const int*)d_in[0];
  const float* action_logps  = (const float*)d_in[1];
  const float* stop_logps    = (const float*)d_in[2];
  const float* start_logps   = (const float*)d_in[3];
  const float* cons_pen      = (const float*)d_in[4];
  float* out = (float*)d_out;

  float* u_ws  = (float*)d_ws;             // 3 * 1024*64 floats = 768 KB
  float* C_ws  = u_ws + T_N * B_N;
  float* Um_ws = C_ws + T_N * B_N;

  hipLaunchKernelGGL(scan_kernel, dim3(1), dim3(64), 0, stream,
                     actions, action_logps, stop_logps, start_logps,
                     out, u_ws, C_ws, Um_ws);
  hipLaunchKernelGGL(cons_kernel, dim3(T_N - 1), dim3(256), 0, stream,
                     actions, action_logps, cons_pen, u_ws, C_ws, Um_ws, out);
}

// Round 3
// 709.053 us; speedup vs baseline: 1.0302x; 1.0302x over previous
//
#include <hip/hip_runtime.h>

#define T_N 1024
#define B_N 64
#define A_N 128
#define TP1 1025
// STOP_IX=0, CONT_IX=1, ABSTRACT_PENALTY=0.5, CONSISTENCY_RATIO=1.0

typedef float f32x4 __attribute__((ext_vector_type(4)));

__device__ __forceinline__ float bcf(int x){ return __builtin_bit_cast(float, x); }
__device__ __forceinline__ int   bci(float x){ return __builtin_bit_cast(int, x); }

// ---- DPP helpers ----
template<int CTRL, int RM>
__device__ __forceinline__ float dpp_add_step(float x){
  int t = __builtin_amdgcn_update_dpp(0, bci(x), CTRL, RM, 0xf, true);
  return x + bcf(t);
}
__device__ __forceinline__ float wave_sum64(float x){
  x = dpp_add_step<0x111,0xf>(x);   // row_shr:1
  x = dpp_add_step<0x112,0xf>(x);   // row_shr:2
  x = dpp_add_step<0x114,0xf>(x);   // row_shr:4
  x = dpp_add_step<0x118,0xf>(x);   // row_shr:8  -> lane15 of each 16-row
  x = dpp_add_step<0x142,0xa>(x);   // row_bcast15
  x = dpp_add_step<0x143,0xc>(x);   // row_bcast31; lane63 = total
  return bcf(__builtin_amdgcn_readlane(bci(x), 63));
}
// sum within each 16-lane group; result lands in lane 15 of each group
__device__ __forceinline__ float group16_sum(float x){
  x = dpp_add_step<0x111,0xf>(x);
  x = dpp_add_step<0x112,0xf>(x);
  x = dpp_add_step<0x114,0xf>(x);
  x = dpp_add_step<0x118,0xf>(x);
  return x;
}
template<int CTRL, int RM>
__device__ __forceinline__ float dpp_max_step(float x){
  int t = __builtin_amdgcn_update_dpp(bci(-3.4e38f), bci(x), CTRL, RM, 0xf, false);
  return fmaxf(x, bcf(t));
}
__device__ __forceinline__ float wave_max64(float x){
  x = dpp_max_step<0x111,0xf>(x);
  x = dpp_max_step<0x112,0xf>(x);
  x = dpp_max_step<0x114,0xf>(x);
  x = dpp_max_step<0x118,0xf>(x);
  x = dpp_max_step<0x142,0xa>(x);
  x = dpp_max_step<0x143,0xc>(x);
  return bcf(__builtin_amdgcn_readlane(bci(x), 63));
}

// =============== K1: serial scan, one wave, 16-deep prefetch ===============
// z[b] = exp(S_{i-1}+C_{i-1}-M)  (power-of-2 rescale keyed to r's exponent).
// Emits: u_ws[i][b] = u_i, D_ws[i][b] = C_i - L_i  (L_i = logsumexp_b(S_i+C_i)),
// zeroes A1, writes out[0] = -(lp0 + fin).  L_i cancels between cons and logp.
__global__ __launch_bounds__(64) void scan_kernel(
    const int* __restrict__ actions,
    const float* __restrict__ action_logps,
    const float* __restrict__ stop_logps,
    const float* __restrict__ start_logps,
    float* __restrict__ out,
    float* __restrict__ u_ws,
    float* __restrict__ D_ws,
    float* __restrict__ A1)
{
  const int lane = threadIdx.x;
  const float KAPPA = 0.60653065971263342f;  // e^-0.5
  const float LN2   = 0.69314718055994531f;

  // zero A1 (1024 floats)
  float4 zf4 = make_float4(0.f,0.f,0.f,0.f);
  ((float4*)A1)[lane]       = zf4;
  ((float4*)A1)[64  + lane] = zf4;
  ((float4*)A1)[128 + lane] = zf4;
  ((float4*)A1)[192 + lane] = zf4;

  float st0 = start_logps[lane];
  int   a0  = actions[0];
  float al0 = action_logps[lane * A_N + a0];
  float lp0 = __logf(wave_sum64(__expf(st0 + al0)));

  float z = __expf(st0);   // M = 0
  float M = 0.f, C = 0.f;
  u_ws[lane] = st0;        // u_0; D row 0 unused

  const float2* stop2 = (const float2*)stop_logps;

  // 16-deep rotating prefetch buffers (all indices static after unroll)
  float2 scb[16]; float stb[16];
  #pragma unroll
  for (int k = 1; k <= 16; ++k) {
    scb[k & 15] = stop2[k * B_N + lane];
    stb[k & 15] = start_logps[k * B_N + lane];
  }
  // stage regs for index 1
  float esw  = __expf(scb[1].x);
  float ecw  = __expf(scb[1].y);
  float estw = __expf(stb[1]) * KAPPA;
  float cont = scb[1].y, stc = stb[1];

  auto step = [&](int i) {
    // prefetch index i+16 into slot i&15 (clamped; junk beyond 1023 never consumed)
    int ipf = i + 16; ipf = ipf > 1023 ? 1023 : ipf;
    scb[i & 15] = stop2[ipf * B_N + lane];
    stb[i & 15] = start_logps[ipf * B_N + lane];

    // critical chain
    float t  = z * esw;
    float zc = z * ecw;
    float r  = wave_sum64(t);
    int rb = bci(r);
    int e  = ((rb >> 23) & 255) - 126;           // r = mr * 2^e, mr in [0.5,1)
    float mr = bcf((rb & 0x007fffff) | 0x3f000000);
    float z2 = ldexpf(zc, -e) + estw * mr;
    M += (float)e * LN2;
    float Ri = M + __logf(mr) - 0.5f;
    C += cont;
    float u = stc + Ri - C;
    u_ws[i * B_N + lane] = u;

    // stage regs for index i+1 (data arrived ~15 iters ago)
    float2 scn = scb[(i + 1) & 15];
    float  stn = stb[(i + 1) & 15];
    esw = __expf(scn.x); ecw = __expf(scn.y); estw = __expf(stn) * KAPPA;
    cont = scn.y; stc = stn;

    // off-critical: L_i, D_i
    float zs = wave_sum64(z2);
    float L  = M + __logf(zs);
    D_ws[i * B_N + lane] = C - L;

    z = z2;
  };

  // main: i = 1..1008 in blocks of 16 (residues static), remainder 1009..1023
  for (int ib = 1; ib < 1009; ib += 16) {
    #pragma unroll
    for (int k = 0; k < 16; ++k) step(ib + k);
  }
  #pragma unroll
  for (int i = 1009; i < T_N; ++i) step(i);

  float stopT = stop_logps[(T_N * B_N + lane) * 2 + 0];
  float fr  = wave_sum64(z * __expf(stopT));
  float fin = M + __logf(fr);
  if (lane == 0) out[0] = -(lp0 + fin);
}

// =============== K2: consistency, block = row j, sequential stream ===============
// A1[i] += sum_b exp(u_j[b] + cp[j][i][b] + D_i[b])   (args <= 0 by construction)
__global__ __launch_bounds__(256) void cons_kernel(
    const float* __restrict__ cons_pen,
    const float* __restrict__ u_ws,
    const float* __restrict__ D_ws,
    float* __restrict__ A1)
{
  const int j    = (int)blockIdx.x;       // 0..1023 (big work first)
  const int tid  = (int)threadIdx.x;
  const int lane = tid & 63;
  const int wv   = tid >> 6;
  const int bq   = (lane & 15) * 4;       // b-quad base
  const int row  = lane >> 4;             // 0..3 -> i offset within quad

  const float4 u4 = *(const float4*)(u_ws + j * B_N + bq);

  for (int i0 = j + 4 * wv; i0 <= 1023; i0 += 16) {
    int i  = i0 + row;
    int iL = i > 1023 ? 1023 : i;
    f32x4 cp4 = __builtin_nontemporal_load(
        (const f32x4*)(cons_pen + ((size_t)j * TP1 + iL) * B_N + bq));
    float4 d4  = *(const float4*)(D_ws + (size_t)iL * B_N + bq);
    bool valid = (i >= 1) && (i <= 1023);
    float a0 = u4.x + d4.x + cp4.x;
    float a1 = u4.y + d4.y + cp4.y;
    float a2 = u4.z + d4.z + cp4.z;
    float a3 = u4.w + d4.w + cp4.w;
    a0 = valid ? a0 : -1e30f;
    a1 = valid ? a1 : -1e30f;
    a2 = valid ? a2 : -1e30f;
    a3 = valid ? a3 : -1e30f;
    float s = (__expf(a0) + __expf(a1)) + (__expf(a2) + __expf(a3));
    s = group16_sum(s);                   // lane 15 of each 16-group has sum over b
    if (((lane & 15) == 15) && valid) atomicAdd(A1 + i, s);
  }
}

// =============== K3: logp terms, parallel over i ===============
// LQ[i] = logsumexp_b( S_i[b] + D_i[b] + act_i[b] )  where S_i = log sum_{j<=i} e^{u_j}
__global__ __launch_bounds__(256) void logp_kernel(
    const int* __restrict__ actions,
    const float* __restrict__ action_logps,
    const float* __restrict__ u_ws,
    const float* __restrict__ D_ws,
    float* __restrict__ LQ)
{
  const int i    = T_N - 1 - (int)blockIdx.x;   // 1023..1, big first
  const int tid  = (int)threadIdx.x;
  const int lane = tid & 63;
  const int wv   = tid >> 6;

  // issue gather early (identical across waves; L1 absorbs the redundancy)
  int   ai = actions[i];
  float av = action_logps[((size_t)i * B_N + lane) * A_N + ai];

  float m = -1e30f, acc = 0.f;
  for (int jj = wv; jj <= i; jj += 4) {
    float u  = u_ws[jj * B_N + lane];
    float nm = fmaxf(m, u);
    acc = acc * __expf(m - nm) + __expf(u - nm);
    m = nm;
  }
  __shared__ float sm[4][64];
  __shared__ float sa[4][64];
  sm[wv][lane] = m; sa[wv][lane] = acc;
  __syncthreads();
  if (wv == 0) {
    float m0 = sm[0][lane], m1 = sm[1][lane], m2 = sm[2][lane], m3 = sm[3][lane];
    float M2 = fmaxf(fmaxf(m0, m1), fmaxf(m2, m3));
    float A  = sa[0][lane] * __expf(m0 - M2) + sa[1][lane] * __expf(m1 - M2)
             + sa[2][lane] * __expf(m2 - M2) + sa[3][lane] * __expf(m3 - M2);
    float S  = M2 + __logf(A);
    float val = S + D_ws[(size_t)i * B_N + lane] + av;
    float mx  = wave_max64(val);
    float sum = wave_sum64(__expf(val - mx));
    if (lane == 0) LQ[i] = mx + __logf(sum);
  }
}

// =============== K4: combine ===============
// out += sum_{i=1}^{1023} ( log A1[i] - LQ[i] )     (the L_i terms cancel)
__global__ __launch_bounds__(256) void finish_kernel(
    const float* __restrict__ A1,
    const float* __restrict__ LQ,
    float* __restrict__ out)
{
  int tid = (int)threadIdx.x;
  float s = 0.f;
  for (int i = 1 + tid; i <= 1023; i += 256) s += __logf(A1[i]) - LQ[i];
  float ws = wave_sum64(s);
  __shared__ float sb[4];
  if ((tid & 63) == 0) sb[tid >> 6] = ws;
  __syncthreads();
  if (tid == 0) atomicAdd(out, sb[0] + sb[1] + sb[2] + sb[3]);
}

extern "C" void kernel_launch(void* const* d_in, const int* in_sizes, int n_in,
                              void* d_out, int out_size, void* d_ws, size_t ws_size,
                              hipStream_t stream) {
  const int*   actions      = (const int*)d_in[0];
  const float* action_logps = (const float*)d_in[1];
  const float* stop_logps   = (const float*)d_in[2];
  const float* start_logps  = (const float*)d_in[3];
  const float* cons_pen     = (const float*)d_in[4];
  float* out = (float*)d_out;

  float* u_ws = (float*)d_ws;              // 1024*64
  float* D_ws = u_ws + T_N * B_N;          // 1024*64 (row 0 unused)
  float* A1   = D_ws + T_N * B_N;          // 1024
  float* LQ   = A1 + T_N;                  // 1024   (total 532 KB)

  hipLaunchKernelGGL(scan_kernel, dim3(1), dim3(64), 0, stream,
                     actions, action_logps, stop_logps, start_logps,
                     out, u_ws, D_ws, A1);
  hipLaunchKernelGGL(cons_kernel, dim3(T_N), dim3(256), 0, stream,
                     cons_pen, u_ws, D_ws, A1);
  hipLaunchKernelGGL(logp_kernel, dim3(T_N - 1), dim3(256), 0, stream,
                     actions, action_logps, u_ws, D_ws, LQ);
  hipLaunchKernelGGL(finish_kernel, dim3(1), dim3(256), 0, stream,
                     A1, LQ, out);
}

// Round 5
// 565.286 us; speedup vs baseline: 1.2923x; 1.2543x over previous
//
#include <hip/hip_runtime.h>

#define T_N 1024
#define B_N 64
#define A_N 128
#define TP1 1025
// STOP_IX=0, CONT_IX=1, ABSTRACT_PENALTY=0.5, CONSISTENCY_RATIO=1.0

typedef float f32x4 __attribute__((ext_vector_type(4)));

__device__ __forceinline__ float bcf(int x){ return __builtin_bit_cast(float, x); }
__device__ __forceinline__ int   bci(float x){ return __builtin_bit_cast(int, x); }

// ---- DPP helpers ----
template<int CTRL, int RM>
__device__ __forceinline__ float dpp_add_step(float x){
  int t = __builtin_amdgcn_update_dpp(0, bci(x), CTRL, RM, 0xf, true);
  return x + bcf(t);
}
__device__ __forceinline__ float wave_sum64(float x){
  x = dpp_add_step<0x111,0xf>(x);   // row_shr:1
  x = dpp_add_step<0x112,0xf>(x);   // row_shr:2
  x = dpp_add_step<0x114,0xf>(x);   // row_shr:4
  x = dpp_add_step<0x118,0xf>(x);   // row_shr:8
  x = dpp_add_step<0x142,0xa>(x);   // row_bcast15
  x = dpp_add_step<0x143,0xc>(x);   // row_bcast31; lane63 = total
  return bcf(__builtin_amdgcn_readlane(bci(x), 63));
}
__device__ __forceinline__ float group16_sum(float x){
  x = dpp_add_step<0x111,0xf>(x);
  x = dpp_add_step<0x112,0xf>(x);
  x = dpp_add_step<0x114,0xf>(x);
  x = dpp_add_step<0x118,0xf>(x);
  return x;                          // lane 15 of each 16-group has group sum
}
template<int CTRL, int RM>
__device__ __forceinline__ float dpp_max_step(float x){
  int t = __builtin_amdgcn_update_dpp(bci(-3.4e38f), bci(x), CTRL, RM, 0xf, false);
  return fmaxf(x, bcf(t));
}
__device__ __forceinline__ float wave_max64(float x){
  x = dpp_max_step<0x111,0xf>(x);
  x = dpp_max_step<0x112,0xf>(x);
  x = dpp_max_step<0x114,0xf>(x);
  x = dpp_max_step<0x118,0xf>(x);
  x = dpp_max_step<0x142,0xa>(x);
  x = dpp_max_step<0x143,0xc>(x);
  return bcf(__builtin_amdgcn_readlane(bci(x), 63));
}

// =============== K1: lean serial scan, one wave ===============
// z[b] tracks y_i[b] = sum_j exp(dist_i[j][b]) with a power-of-2 scale 2^-P,
// rescaled once per 16 steps (keyed to r's exponent). Emits raw z rows,
// raw r_i (uniform store), and per-window exponents. No logs in loop.
__global__ __launch_bounds__(64, 1) void scan_kernel(
    const float* __restrict__ stop_logps,
    const float* __restrict__ start_logps,
    float* __restrict__ z_ws,     // (1024,64) rows 1..1023
    float* __restrict__ r_ws,     // 1024
    float* __restrict__ wexp)     // 64 (0..62 used)
{
  const int lane = threadIdx.x;
  const float KAPPA = 0.60653065971263342f;  // e^-0.5
  const float2* stop2 = (const float2*)stop_logps;

  float st0 = start_logps[lane];
  float z = __expf(st0);                     // y_0, scale P=0

  // 16-deep rotating prefetch (static indices after unroll; launch_bounds(64,1)
  // gives the register budget so these stay in VGPRs)
  float2 scb[16]; float stb[16];
  #pragma unroll
  for (int k = 1; k <= 16; ++k) {
    scb[k & 15] = stop2[k * B_N + lane];
    stb[k & 15] = start_logps[k * B_N + lane];
  }
  float esw  = __expf(scb[1].x);
  float ecw  = __expf(scb[1].y);
  float estw = __expf(stb[1]) * KAPPA;

  for (int ib = 1; ib < 1009; ib += 16) {
    #pragma unroll
    for (int k = 0; k < 16; ++k) {
      const int i = ib + k;
      // prefetch i+16 (i <= 1008 -> index <= 1024, valid: arrays have 1025 rows)
      scb[i & 15] = stop2[(i + 16) * B_N + lane];
      stb[i & 15] = start_logps[(i + 16) * B_N + lane];

      // critical chain: mul -> 6 DPP -> readlane -> fmac
      float t  = z * esw;
      float zc = z * ecw;
      float r  = wave_sum64(t);
      z = __builtin_fmaf(estw, r, zc);
      z_ws[i * B_N + lane] = z;
      r_ws[i] = r;                   // uniform store (all lanes, same addr/value)

      // stage exps for i+1 (loads landed ~15 iters ago)
      float2 scn = scb[(i + 1) & 15];
      float  stn = stb[(i + 1) & 15];
      esw = __expf(scn.x); ecw = __expf(scn.y); estw = __expf(stn) * KAPPA;

      if (k == 15) {
        int rb = bci(r);
        int e16 = ((rb >> 23) & 255) - 127;
        z = ldexpf(z, -e16);         // window rescale; P += e16
        wexp[ib >> 4] = (float)e16;  // ib = 1+16m -> m
      }
    }
  }
  #pragma unroll
  for (int i = 1009; i < T_N; ++i) {   // window 63, no rescale
    float t  = z * esw;
    float zc = z * ecw;
    float r  = wave_sum64(t);
    z = __builtin_fmaf(estw, r, zc);
    z_ws[i * B_N + lane] = z;
    r_ws[i] = r;
    float2 scn = scb[(i + 1) & 15];
    float  stn = stb[(i + 1) & 15];
    esw = __expf(scn.x); ecw = __expf(scn.y); estw = __expf(stn) * KAPPA;
  }
}

// =============== K2: parallel bookkeeping ===============
// Reconstructs C_i (block prefix over cont), u_i = st_i + R_i - C_i,
// D_i = C_i - L_i, zeros A1p, writes out[0] = -(lp0 + fin).
__global__ __launch_bounds__(1024) void post_kernel(
    const int* __restrict__ actions,
    const float* __restrict__ action_logps,
    const float* __restrict__ stop_logps,
    const float* __restrict__ start_logps,
    const float* __restrict__ z_ws,
    const float* __restrict__ r_ws,
    const float* __restrict__ wexp,
    float* __restrict__ u_ws,
    float* __restrict__ D_ws,
    float* __restrict__ A1p,
    float* __restrict__ out)
{
  const int tid  = (int)threadIdx.x;
  const int w    = tid >> 6;     // 0..15
  const int lane = tid & 63;     // = b
  const float LN2 = 0.69314718055994531f;
  const float2* stop2 = (const float2*)stop_logps;

  __shared__ float ts[16][64];
  __shared__ float Pw[64];

  // zero A1p (64 x 1024)
  #pragma unroll 4
  for (int p = 0; p < 64; ++p) A1p[p * 1024 + tid] = 0.f;

  // phase A: per-wave cont partial sums over i in [64w+1, 64w+64]
  float s = 0.f;
  for (int k = 1; k <= 64; ++k) {
    int i = 64 * w + k;
    if (i <= 1023) s += stop2[i * B_N + lane].y;
  }
  ts[w][lane] = s;
  if (w == 0) {   // window-scale prefix: Pw[m] = ln2 * sum_{m'<m} wexp[m']
    float p = 0.f;
    for (int m = 0; m < lane && m < 63; ++m) p += wexp[m];
    Pw[lane] = p * LN2;
  }
  __syncthreads();

  float C = 0.f;
  for (int ww = 0; ww < w; ++ww) C += ts[ww][lane];
  for (int k = 1; k <= 64; ++k) {
    int i = 64 * w + k;
    if (i > 1023) break;
    C += stop2[i * B_N + lane].y;
    float Pv = Pw[(i - 1) >> 4];
    float R  = __logf(r_ws[i]) + Pv - 0.5f;
    u_ws[i * B_N + lane] = start_logps[i * B_N + lane] + R - C;
    float zs = wave_sum64(z_ws[i * B_N + lane]);
    D_ws[i * B_N + lane] = C - (__logf(zs) + Pv);
  }
  if (tid < 64) u_ws[lane] = start_logps[lane];   // u_0 = st0

  if (w == 15) {
    float st0 = start_logps[lane];
    int   a0  = actions[0];
    float al0 = action_logps[lane * A_N + a0];
    float lp0 = __logf(wave_sum64(__expf(st0 + al0)));
    float stopT = stop_logps[(T_N * B_N + lane) * 2 + 0];
    float z1023 = z_ws[1023 * B_N + lane];
    float fin = __logf(wave_sum64(z1023 * __expf(stopT))) + Pw[63];
    if (lane == 0) out[0] = -(lp0 + fin);
  }
}

// =============== K3: consistency, block = row j, sequential stream ===============
// A1p[j&63][i] += sum_b exp(u_j[b] + cp[j][i][b] + D_i[b])
__global__ __launch_bounds__(256) void cons_kernel(
    const float* __restrict__ cons_pen,
    const float* __restrict__ u_ws,
    const float* __restrict__ D_ws,
    float* __restrict__ A1p)
{
  const int j    = (int)blockIdx.x;       // 0 = biggest row first
  const int tid  = (int)threadIdx.x;
  const int lane = tid & 63;
  const int wv   = tid >> 6;
  const int bq   = (lane & 15) * 4;
  const int row  = lane >> 4;

  const float4 u4 = *(const float4*)(u_ws + j * B_N + bq);
  float* dst = A1p + ((j & 63) << 10);

  for (int i0 = j + 4 * wv; i0 <= 1023; i0 += 16) {
    int i  = i0 + row;
    int iL = i > 1023 ? 1023 : i;
    f32x4 cp4 = __builtin_nontemporal_load(
        (const f32x4*)(cons_pen + ((size_t)j * TP1 + iL) * B_N + bq));
    float4 d4  = *(const float4*)(D_ws + (size_t)iL * B_N + bq);
    bool valid = (i >= 1) && (i <= 1023);
    float a0 = u4.x + d4.x + cp4.x;
    float a1 = u4.y + d4.y + cp4.y;
    float a2 = u4.z + d4.z + cp4.z;
    float a3 = u4.w + d4.w + cp4.w;
    a0 = valid ? a0 : -1e30f;
    a1 = valid ? a1 : -1e30f;
    a2 = valid ? a2 : -1e30f;
    a3 = valid ? a3 : -1e30f;
    float sred = (__expf(a0) + __expf(a1)) + (__expf(a2) + __expf(a3));
    sred = group16_sum(sred);
    if (((lane & 15) == 15) && valid) atomicAdd(dst + i, sred);
  }
}

// =============== K4: logp terms, parallel over i ===============
__global__ __launch_bounds__(256) void logp_kernel(
    const int* __restrict__ actions,
    const float* __restrict__ action_logps,
    const float* __restrict__ u_ws,
    const float* __restrict__ D_ws,
    float* __restrict__ LQ)
{
  const int i    = T_N - 1 - (int)blockIdx.x;   // 1023..1
  const int tid  = (int)threadIdx.x;
  const int lane = tid & 63;
  const int wv   = tid >> 6;

  int   ai = actions[i];
  float av = action_logps[((size_t)i * B_N + lane) * A_N + ai];

  float m = -1e30f, acc = 0.f;
  for (int jj = wv; jj <= i; jj += 4) {
    float u  = u_ws[jj * B_N + lane];
    float nm = fmaxf(m, u);
    acc = acc * __expf(m - nm) + __expf(u - nm);
    m = nm;
  }
  __shared__ float sm[4][64];
  __shared__ float sa[4][64];
  sm[wv][lane] = m; sa[wv][lane] = acc;
  __syncthreads();
  if (wv == 0) {
    float m0 = sm[0][lane], m1 = sm[1][lane], m2 = sm[2][lane], m3 = sm[3][lane];
    float M2 = fmaxf(fmaxf(m0, m1), fmaxf(m2, m3));
    float A  = sa[0][lane] * __expf(m0 - M2) + sa[1][lane] * __expf(m1 - M2)
             + sa[2][lane] * __expf(m2 - M2) + sa[3][lane] * __expf(m3 - M2);
    float S  = M2 + __logf(A);
    float val = S + D_ws[(size_t)i * B_N + lane] + av;
    float mx  = wave_max64(val);
    float sum = wave_sum64(__expf(val - mx));
    if (lane == 0) LQ[i] = mx + __logf(sum);
  }
}

// =============== K5: combine ===============
__global__ __launch_bounds__(256) void finish_kernel(
    const float* __restrict__ A1p,
    const float* __restrict__ LQ,
    float* __restrict__ out)
{
  const int i = (int)blockIdx.x * 256 + (int)threadIdx.x;   // grid 4
  float v = 0.f;
  if (i >= 1 && i <= 1023) {
    float a = 0.f;
    #pragma unroll 8
    for (int p = 0; p < 64; ++p) a += A1p[(p << 10) + i];
    v = __logf(a) - LQ[i];
  }
  float ws = wave_sum64(v);
  __shared__ float sb[4];
  if ((threadIdx.x & 63) == 0) sb[threadIdx.x >> 6] = ws;
  __syncthreads();
  if (threadIdx.x == 0) atomicAdd(out, sb[0] + sb[1] + sb[2] + sb[3]);
}

extern "C" void kernel_launch(void* const* d_in, const int* in_sizes, int n_in,
                              void* d_out, int out_size, void* d_ws, size_t ws_size,
                              hipStream_t stream) {
  const int*   actions      = (const int*)d_in[0];
  const float* action_logps = (const float*)d_in[1];
  const float* stop_logps   = (const float*)d_in[2];
  const float* start_logps  = (const float*)d_in[3];
  const float* cons_pen     = (const float*)d_in[4];
  float* out = (float*)d_out;

  float* z_ws = (float*)d_ws;                 // 1024*64
  float* u_ws = z_ws + T_N * B_N;             // 1024*64
  float* D_ws = u_ws + T_N * B_N;             // 1024*64
  float* A1p  = D_ws + T_N * B_N;             // 64*1024
  float* r_ws = A1p + 64 * 1024;              // 1024
  float* wexp = r_ws + T_N;                   // 64
  float* LQ   = wexp + 64;                    // 1024   (total ~1.04 MB)

  hipLaunchKernelGGL(scan_kernel, dim3(1), dim3(64), 0, stream,
                     stop_logps, start_logps, z_ws, r_ws, wexp);
  hipLaunchKernelGGL(post_kernel, dim3(1), dim3(1024), 0, stream,
                     actions, action_logps, stop_logps, start_logps,
                     z_ws, r_ws, wexp, u_ws, D_ws, A1p, out);
  hipLaunchKernelGGL(cons_kernel, dim3(T_N), dim3(256), 0, stream,
                     cons_pen, u_ws, D_ws, A1p);
  hipLaunchKernelGGL(logp_kernel, dim3(T_N - 1), dim3(256), 0, stream,
                     actions, action_logps, u_ws, D_ws, LQ);
  hipLaunchKernelGGL(finish_kernel, dim3(4), dim3(256), 0, stream,
                     A1p, LQ, out);
}